// Round 4
// baseline (130.988 us; speedup 1.0000x reference)
//
#include <hip/hip_runtime.h>
#include <hip/hip_bf16.h>

#define N0 300000
#define N1 60000
#define N2 6000
#define E1 1200000
#define E2 300000
#define D 128
#define DO 64

typedef __attribute__((ext_vector_type(8))) short bfrag8;
typedef __attribute__((ext_vector_type(4))) float f32x4;

#define WL_CAP 32768
#define UC_CAP 256
#define INIT_BLOCKS 1875           // x 256 thr x 4 iters = N1*32 float4-units
#define SCAN_BLOCKS 4688           // x 256 >= E1

__device__ __forceinline__ float bf2f(unsigned int u) {
    union { unsigned int i; float f; } c; c.i = u << 16; return c.f;
}
__device__ __forceinline__ unsigned short f2bf(float f) {
    return __bfloat16_as_ushort(__float2bfloat16(f));
}

// ---- 1. zero the small accumulators (replaces hipMemsetAsync / rocclr fill) ----
__global__ void k_zero(float* __restrict__ statsfix, int* __restrict__ cnt,
                       int* __restrict__ nuc, int* __restrict__ ehist) {
    int b = blockIdx.x, t = threadIdx.x;
    if (b == 0) {
        statsfix[t] = 0.f;
        if (t == 0) { *cnt = 0; *nuc = 0; }
    }
    int hi = (b + 1) * 750; if (hi > N2) hi = N2;
    for (int i = b * 750 + t; i < hi; i += 256) ehist[i] = 0;
}

// ---- 2. phase1: [0,1875) init hb (pre-BN bf16) + per-block stats partials;
//                 [1875,6563) worklist scan + layer-2 dst histogram ----
__global__ void __launch_bounds__(256) k_phase1(
        const float* __restrict__ x, const int* __restrict__ hmap,
        const float* __restrict__ hist, const float* __restrict__ Wself1,
        const float* __restrict__ b1, unsigned short* __restrict__ hb,
        int* __restrict__ nuc, int* __restrict__ uc_slot,
        int* __restrict__ uc_node, float* __restrict__ hfix,
        float* __restrict__ psum,
        const int* __restrict__ dst1, int* __restrict__ cnt,
        int* __restrict__ list, const int* __restrict__ dst2,
        int* __restrict__ ehist) {
    int b = blockIdx.x, tid = threadIdx.x;
    if (b >= INIT_BLOCKS) {
        int e = (b - INIT_BLOCKS) * 256 + tid;
        if (e < E2) atomicAdd(&ehist[dst2[e]], 1);
        if (e < E1 && hmap[dst1[e]] < 0) {
            int i = atomicAdd(cnt, 1);
            if (i < WL_CAP) list[i] = e;
        }
        return;
    }
    __shared__ float ls1[1024], ls2[1024];
    int lane = tid & 63, q = tid & 31;
    float a1[4] = {0.f, 0.f, 0.f, 0.f}, a2[4] = {0.f, 0.f, 0.f, 0.f};
#pragma unroll
    for (int it = 0; it < 4; it++) {
        int idx = (b * 4 + it) * 256 + tid;      // q invariant across iters
        int node = idx >> 5;
        int m = hmap[node];
        float v[4];
        if (m >= 0) {
            float4 hv = ((const float4*)hist)[m * 32 + q];
            v[0] = hv.x; v[1] = hv.y; v[2] = hv.z; v[3] = hv.w;
        } else {
            int slot = -1;
            if (q == 0) {
                slot = atomicAdd(nuc, 1);
                if (slot < UC_CAP) { uc_slot[node] = slot; uc_node[slot] = node; }
            }
            slot = __shfl(slot, lane & 32, 64);
#pragma unroll
            for (int j = 0; j < 4; j++) v[j] = b1[q * 4 + j];
            for (int k = 0; k < D; k++) {
                float xv = x[(size_t)node * D + k];
#pragma unroll
                for (int j = 0; j < 4; j++) v[j] += xv * Wself1[k * D + q * 4 + j];
            }
            if (slot >= 0 && slot < UC_CAP) {
#pragma unroll
                for (int j = 0; j < 4; j++) hfix[slot * D + q * 4 + j] = v[j];
            }
        }
#pragma unroll
        for (int j = 0; j < 4; j++) { a1[j] += v[j]; a2[j] += v[j] * v[j]; }
        union { unsigned short s[4]; uint2 u; } o;
#pragma unroll
        for (int j = 0; j < 4; j++) o.s[j] = f2bf(v[j]);
        *(uint2*)(hb + (size_t)idx * 4) = o.u;
    }
#pragma unroll
    for (int j = 0; j < 4; j++) { ls1[tid * 4 + j] = a1[j]; ls2[tid * 4 + j] = a2[j]; }
    __syncthreads();
    if (tid < 128) {
        int qq = tid >> 2, jj = tid & 3;         // col c = tid
        float S = 0.f, SS = 0.f;
#pragma unroll
        for (int g = 0; g < 8; g++) {
            int src = (qq + 32 * g) * 4 + jj;
            S += ls1[src]; SS += ls2[src];
        }
        psum[b * 256 + tid] = S;
        psum[b * 256 + 128 + tid] = SS;
    }
}

// ---- 3. [0,16): worklist edges into hfix + telescoping stats fix;
//         [16,31): psum 1875-row reduce to psum2 15 rows ----
__global__ void k_wl2(const float* __restrict__ x, const int* __restrict__ src1,
                      const int* __restrict__ dst1, const int* __restrict__ et1,
                      const float* __restrict__ W1, const int* __restrict__ cnt,
                      const int* __restrict__ list, const int* __restrict__ uc_slot,
                      float* __restrict__ hfix, float* __restrict__ statsfix,
                      const float* __restrict__ psum, float* __restrict__ psum2) {
    int b = blockIdx.x, tid = threadIdx.x;
    if (b >= 16) {
        int r = b - 16, base = r * 125;
        float S = 0.f;
        for (int i = 0; i < 125; i++) S += psum[(base + i) * 256 + tid];
        psum2[r * 256 + tid] = S;
        return;
    }
    int c = tid & 127, half = tid >> 7;
    int n = *cnt; if (n > WL_CAP) n = WL_CAP;
    for (int i = b * 2 + half; i < n; i += 32) {
        int e = list[i];
        int s = src1[e], d = dst1[e], t = et1[e];
        int slot = uc_slot[d];
        if (slot < 0 || slot >= UC_CAP) continue;
        float acc = 0.f;
        for (int k = 0; k < D; k++) acc += x[(size_t)s * D + k] * W1[(t * D + k) * D + c];
        float old = atomicAdd(&hfix[slot * D + c], acc);
        atomicAdd(&statsfix[c], acc);
        atomicAdd(&statsfix[128 + c], 2.f * old * acc + acc * acc);
    }
}

// ---- 4. block 0: CSR scan; block 1: BN params; [2,162): B-frag pack;
//         [162,170): uncached rows -> hb (pre-BN, f32-complete) ----
__global__ void k_mid(const int* __restrict__ ehist, int* __restrict__ rs,
                      int* __restrict__ rs2, const float* __restrict__ psum2,
                      const float* __restrict__ statsfix,
                      const float* __restrict__ gamma, const float* __restrict__ beta,
                      float* __restrict__ params,
                      const float* __restrict__ W2, const float* __restrict__ Wself2,
                      unsigned short* __restrict__ BF,
                      const int* __restrict__ nuc, const int* __restrict__ uc_node,
                      const float* __restrict__ hfix, unsigned short* __restrict__ hb) {
    int b = blockIdx.x, tid = threadIdx.x;
    if (b == 1) {
        if (tid < 128) {
            float S = statsfix[tid], SS = statsfix[128 + tid];
#pragma unroll
            for (int r = 0; r < 15; r++) {
                S += psum2[r * 256 + tid];
                SS += psum2[r * 256 + 128 + tid];
            }
            float mean = S / (float)N1;
            float var = SS / (float)N1 - mean * mean;
            float sc = gamma[tid] * rsqrtf(var + 1e-5f);
            params[tid] = sc;
            params[128 + tid] = beta[tid] - mean * sc;
        }
        return;
    }
    if (b >= 162) {
        int n = *nuc; if (n > UC_CAP) n = UC_CAP;
        int c = tid & 127, sub = tid >> 7;
        for (int slot = (b - 162) * 2 + sub; slot < n; slot += 16) {
            int node = uc_node[slot];
            hb[(size_t)node * D + c] = f2bf(hfix[slot * D + c]);
        }
        return;
    }
    if (b >= 2) {
        int idx = (b - 2) * 256 + tid;           // 5*16*64*8 = 40960 exactly
        int j = idx & 7, lane = (idx >> 3) & 63, sub = (idx >> 9) & 15, g = idx >> 13;
        int kt = sub >> 2, ct = sub & 3;
        int k = kt * 32 + (lane >> 4) * 8 + j;
        int col = ct * 16 + (lane & 15);
        float v = (g < 4) ? W2[(g * D + k) * DO + col] : Wself2[k * DO + col];
        BF[idx] = f2bf(v);
        return;
    }
    // b == 0: exclusive scan of ehist
    __shared__ int part[256];
    int lo = tid * 24, hi = lo + 24; if (hi > N2) hi = N2;
    int s = 0;
    for (int i = lo; i < hi; i++) s += ehist[i];
    part[tid] = s;
    __syncthreads();
    if (tid == 0) {
        int a = 0;
        for (int i = 0; i < 256; i++) { int v = part[i]; part[i] = a; a += v; }
        rs[N2] = a;
    }
    __syncthreads();
    int a = part[tid];
    for (int i = lo; i < hi; i++) { rs[i] = a; rs2[i] = a; a += ehist[i]; }
}

// ---- 5. CSR scatter of layer-2 edges ----
__global__ void k_escatter(const int* __restrict__ src2, const int* __restrict__ dst2,
                           const int* __restrict__ et2, int* __restrict__ rs2,
                           int* __restrict__ epay) {
    int e = blockIdx.x * blockDim.x + threadIdx.x;
    if (e >= E2) return;
    int d = dst2[e];
    int pos = atomicAdd(&rs2[d], 1);
    epay[pos] = src2[e] | (et2[e] << 16);
}

// ---- 6. aggregate: per-dst per-relation sum of relu(bn(hb[src])) rows ----
#define AGG_ACC(P, V) { \
    int t_ = (P) >> 16; \
    float f0_ = fmaxf(bf2f((V) & 0xffff) * sc0 + sh0, 0.f); \
    float f1_ = fmaxf(bf2f((V) >> 16) * sc1 + sh1, 0.f); \
    acc[0][0] += (t_ == 0) ? f0_ : 0.f; acc[0][1] += (t_ == 0) ? f1_ : 0.f; \
    acc[1][0] += (t_ == 1) ? f0_ : 0.f; acc[1][1] += (t_ == 1) ? f1_ : 0.f; \
    acc[2][0] += (t_ == 2) ? f0_ : 0.f; acc[2][1] += (t_ == 2) ? f1_ : 0.f; \
    acc[3][0] += (t_ == 3) ? f0_ : 0.f; acc[3][1] += (t_ == 3) ? f1_ : 0.f; }

__global__ void __launch_bounds__(256) k_agg(const unsigned int* __restrict__ hbu,
                                             const int* __restrict__ rs,
                                             const int* __restrict__ epay,
                                             const float* __restrict__ params,
                                             unsigned int* __restrict__ aggbu) {
    int wave = threadIdx.x >> 6, lane = threadIdx.x & 63;
    int d = blockIdx.x * 4 + wave;
    if (d >= N2) return;
    float sc0 = params[2 * lane],       sh0 = params[128 + 2 * lane];
    float sc1 = params[2 * lane + 1],   sh1 = params[128 + 2 * lane + 1];
    float acc[4][2] = {};
    int j0 = rs[d], j1 = rs[d + 1];
    int j = j0;
    for (; j + 4 <= j1; j += 4) {
        int p0 = epay[j], p1 = epay[j + 1], p2 = epay[j + 2], p3 = epay[j + 3];
        unsigned int v0 = hbu[(size_t)(p0 & 0xffff) * 64 + lane];
        unsigned int v1 = hbu[(size_t)(p1 & 0xffff) * 64 + lane];
        unsigned int v2 = hbu[(size_t)(p2 & 0xffff) * 64 + lane];
        unsigned int v3 = hbu[(size_t)(p3 & 0xffff) * 64 + lane];
        AGG_ACC(p0, v0); AGG_ACC(p1, v1); AGG_ACC(p2, v2); AGG_ACC(p3, v3);
    }
    for (; j < j1; j++) {
        int p = epay[j];
        unsigned int v = hbu[(size_t)(p & 0xffff) * 64 + lane];
        AGG_ACC(p, v);
    }
#pragma unroll
    for (int t = 0; t < 4; t++) {
        unsigned int o = (unsigned int)f2bf(acc[t][0]) | ((unsigned int)f2bf(acc[t][1]) << 16);
        aggbu[((size_t)t * N2 + d) * 64 + lane] = o;
    }
}

// ---- 7. out[d] = logsoftmax(b2 + relu(bn(hb[d]))@Wself2 + sum_t agg[t][d]@W2[t]) ----
__global__ void __launch_bounds__(256) k_gemm2(const unsigned short* __restrict__ aggb,
                                               const unsigned short* __restrict__ hb,
                                               const unsigned short* __restrict__ BF,
                                               const float* __restrict__ params,
                                               const float* __restrict__ b2,
                                               float* __restrict__ out) {
    int row0 = blockIdx.x * 64;
    int wave = threadIdx.x >> 6, lane = threadIdx.x & 63;
    int r = row0 + wave * 16 + (lane & 15);
    int rl = (r < N2) ? r : N2 - 1;
    int kb = (lane >> 4) * 8;
    f32x4 acc[4] = {};
#pragma unroll
    for (int kt = 0; kt < 4; kt++) {
#pragma unroll
        for (int g = 0; g < 5; g++) {
            bfrag8 a;
            if (g < 4) {
                a = *reinterpret_cast<const bfrag8*>(aggb + ((size_t)(g * N2 + rl) * D + kt * 32 + kb));
            } else {
                bfrag8 raw = *reinterpret_cast<const bfrag8*>(hb + ((size_t)rl * D + kt * 32 + kb));
#pragma unroll
                for (int j = 0; j < 8; j++) {
                    int c = kt * 32 + kb + j;
                    float f = bf2f((unsigned int)(unsigned short)raw[j]);
                    f = fmaxf(f * params[c] + params[128 + c], 0.f);
                    a[j] = (short)f2bf(f);
                }
            }
#pragma unroll
            for (int ct = 0; ct < 4; ct++) {
                bfrag8 bb = *reinterpret_cast<const bfrag8*>(BF + ((((g * 4 + kt) * 4 + ct) * 64 + lane) * 8));
                acc[ct] = __builtin_amdgcn_mfma_f32_16x16x32_bf16(a, bb, acc[ct], 0, 0, 0);
            }
        }
    }
    float bb4[4];
#pragma unroll
    for (int ct = 0; ct < 4; ct++) bb4[ct] = b2[ct * 16 + (lane & 15)];
    int srow = row0 + wave * 16 + (lane >> 4) * 4;
#pragma unroll
    for (int i = 0; i < 4; i++) {
        float v[4];
#pragma unroll
        for (int ct = 0; ct < 4; ct++) v[ct] = acc[ct][i] + bb4[ct];
        float m = fmaxf(fmaxf(v[0], v[1]), fmaxf(v[2], v[3]));
#pragma unroll
        for (int sh = 1; sh <= 8; sh <<= 1) m = fmaxf(m, __shfl_xor(m, sh, 64));
        float s = 0.f;
#pragma unroll
        for (int ct = 0; ct < 4; ct++) s += expf(v[ct] - m);
#pragma unroll
        for (int sh = 1; sh <= 8; sh <<= 1) s += __shfl_xor(s, sh, 64);
        float lg = m + logf(s);
        int rr = srow + i;
        if (rr < N2) {
#pragma unroll
            for (int ct = 0; ct < 4; ct++)
                out[(size_t)rr * DO + ct * 16 + (lane & 15)] = v[ct] - lg;
        }
    }
}

extern "C" void kernel_launch(void* const* d_in, const int* in_sizes, int n_in,
                              void* d_out, int out_size, void* d_ws, size_t ws_size,
                              hipStream_t stream) {
    const float* x      = (const float*)d_in[0];
    const int* src1     = (const int*)d_in[1];
    const int* dst1     = (const int*)d_in[2];
    const int* et1      = (const int*)d_in[3];
    const int* src2     = (const int*)d_in[4];
    const int* dst2     = (const int*)d_in[5];
    const int* et2      = (const int*)d_in[6];
    const int* hmap     = (const int*)d_in[7];
    const float* hist   = (const float*)d_in[8];
    const float* W1     = (const float*)d_in[9];
    const float* Wself1 = (const float*)d_in[10];
    const float* b1     = (const float*)d_in[11];
    const float* gamma  = (const float*)d_in[12];
    const float* beta   = (const float*)d_in[13];
    const float* W2     = (const float*)d_in[14];
    const float* Wself2 = (const float*)d_in[15];
    const float* b2     = (const float*)d_in[16];
    float* out = (float*)d_out;

    char* ws = (char*)d_ws;
    unsigned short* hb   = (unsigned short*)(ws);              // 15,360,000
    unsigned short* aggb = (unsigned short*)(ws + 15360000);   //  6,144,000
    unsigned short* BF   = (unsigned short*)(ws + 21504000);   //     81,920
    float* hfix          = (float*)(ws + 21585920);            //    131,072
    int* uc_node         = (int*)(ws + 21716992);              //      1,024
    int* uc_slot         = (int*)(ws + 21718016);              //    240,000
    int* epay            = (int*)(ws + 21958016);              //  1,200,000
    int* rs              = (int*)(ws + 23158016);              //     24,016
    int* rs2             = (int*)(ws + 23182032);              //     24,000
    float* psum          = (float*)(ws + 23206032);            //  1,920,000
    float* psum2         = (float*)(ws + 25126032);            //     15,360
    float* statsfix      = (float*)(ws + 25141392);            //      1,024
    int* cnt             = (int*)(ws + 25142416);              //          4
    int* nuc             = (int*)(ws + 25142420);              //          4
    int* ehist           = (int*)(ws + 25142424);              //     24,000
    int* list            = (int*)(ws + 25166424);              //    131,072
    float* params        = (float*)(ws + 25297496);            //      1,024

    k_zero<<<8, 256, 0, stream>>>(statsfix, cnt, nuc, ehist);
    k_phase1<<<INIT_BLOCKS + SCAN_BLOCKS, 256, 0, stream>>>(
        x, hmap, hist, Wself1, b1, hb, nuc, uc_slot, uc_node, hfix, psum,
        dst1, cnt, list, dst2, ehist);
    k_wl2<<<31, 256, 0, stream>>>(x, src1, dst1, et1, W1, cnt, list, uc_slot,
                                  hfix, statsfix, psum, psum2);
    k_mid<<<170, 256, 0, stream>>>(ehist, rs, rs2, psum2, statsfix, gamma, beta,
                                   params, W2, Wself2, BF, nuc, uc_node, hfix, hb);
    k_escatter<<<(E2 + 255) / 256, 256, 0, stream>>>(src2, dst2, et2, rs2, epay);
    k_agg<<<1500, 256, 0, stream>>>((const unsigned int*)hb, rs, epay, params,
                                    (unsigned int*)aggb);
    k_gemm2<<<94, 256, 0, stream>>>(aggb, hb, BF, params, b2, out);
}

// Round 5
// 129.173 us; speedup vs baseline: 1.0140x; 1.0140x over previous
//
#include <hip/hip_runtime.h>
#include <hip/hip_bf16.h>

#define N0 300000
#define N1 60000
#define N2 6000
#define E1 1200000
#define E2 300000
#define D 128
#define DO 64

typedef __attribute__((ext_vector_type(8))) short bfrag8;
typedef __attribute__((ext_vector_type(4))) float f32x4;

#define WL_CAP 32768
#define UC_CAP 256
#define INIT_BLOCKS 1875           // x 256 thr x 4 iters = N1*32 float4-units
#define SCAN_BLOCKS 4688           // x 256 >= E1

__device__ __forceinline__ float bf2f(unsigned int u) {
    union { unsigned int i; float f; } c; c.i = u << 16; return c.f;
}
__device__ __forceinline__ unsigned short f2bf(float f) {
    return __bfloat16_as_ushort(__float2bfloat16(f));
}

// ---- 1. zero the small accumulators ----
__global__ void k_zero(float* __restrict__ statsfix, int* __restrict__ cnt,
                       int* __restrict__ nuc, int* __restrict__ ehist) {
    int b = blockIdx.x, t = threadIdx.x;
    if (b == 0) {
        statsfix[t] = 0.f;
        if (t == 0) { *cnt = 0; *nuc = 0; }
    }
    int hi = (b + 1) * 750; if (hi > N2) hi = N2;
    for (int i = b * 750 + t; i < hi; i += 256) ehist[i] = 0;
}

// ---- 2. phase1: [0,1875) init hb (pre-BN bf16) + per-block stats partials;
//                 [1875,6563) worklist scan + layer-2 dst histogram ----
__global__ void __launch_bounds__(256) k_phase1(
        const float* __restrict__ x, const int* __restrict__ hmap,
        const float* __restrict__ hist, const float* __restrict__ Wself1,
        const float* __restrict__ b1, unsigned short* __restrict__ hb,
        int* __restrict__ nuc, int* __restrict__ uc_slot,
        int* __restrict__ uc_node, float* __restrict__ hfix,
        float* __restrict__ psum,
        const int* __restrict__ dst1, int* __restrict__ cnt,
        int* __restrict__ list, const int* __restrict__ dst2,
        int* __restrict__ ehist) {
    int b = blockIdx.x, tid = threadIdx.x;
    if (b >= INIT_BLOCKS) {
        int e = (b - INIT_BLOCKS) * 256 + tid;
        if (e < E2) atomicAdd(&ehist[dst2[e]], 1);
        if (e < E1 && hmap[dst1[e]] < 0) {
            int i = atomicAdd(cnt, 1);
            if (i < WL_CAP) list[i] = e;
        }
        return;
    }
    __shared__ float ls1[1024], ls2[1024];
    int lane = tid & 63, q = tid & 31;
    float a1[4] = {0.f, 0.f, 0.f, 0.f}, a2[4] = {0.f, 0.f, 0.f, 0.f};
#pragma unroll
    for (int it = 0; it < 4; it++) {
        int idx = (b * 4 + it) * 256 + tid;      // q invariant across iters
        int node = idx >> 5;
        int m = hmap[node];
        float v[4];
        if (m >= 0) {
            float4 hv = ((const float4*)hist)[m * 32 + q];
            v[0] = hv.x; v[1] = hv.y; v[2] = hv.z; v[3] = hv.w;
        } else {
            int slot = -1;
            if (q == 0) {
                slot = atomicAdd(nuc, 1);
                if (slot < UC_CAP) { uc_slot[node] = slot; uc_node[slot] = node; }
            }
            slot = __shfl(slot, lane & 32, 64);
#pragma unroll
            for (int j = 0; j < 4; j++) v[j] = b1[q * 4 + j];
            for (int k = 0; k < D; k++) {
                float xv = x[(size_t)node * D + k];
#pragma unroll
                for (int j = 0; j < 4; j++) v[j] += xv * Wself1[k * D + q * 4 + j];
            }
            if (slot >= 0 && slot < UC_CAP) {
#pragma unroll
                for (int j = 0; j < 4; j++) hfix[slot * D + q * 4 + j] = v[j];
            }
        }
#pragma unroll
        for (int j = 0; j < 4; j++) { a1[j] += v[j]; a2[j] += v[j] * v[j]; }
        union { unsigned short s[4]; uint2 u; } o;
#pragma unroll
        for (int j = 0; j < 4; j++) o.s[j] = f2bf(v[j]);
        *(uint2*)(hb + (size_t)idx * 4) = o.u;
    }
#pragma unroll
    for (int j = 0; j < 4; j++) { ls1[tid * 4 + j] = a1[j]; ls2[tid * 4 + j] = a2[j]; }
    __syncthreads();
    if (tid < 128) {
        int qq = tid >> 2, jj = tid & 3;         // col c = tid
        float S = 0.f, SS = 0.f;
#pragma unroll
        for (int g = 0; g < 8; g++) {
            int src = (qq + 32 * g) * 4 + jj;
            S += ls1[src]; SS += ls2[src];
        }
        psum[b * 256 + tid] = S;
        psum[b * 256 + 128 + tid] = SS;
    }
}

// ---- 3. [0,16): worklist edges into hfix + telescoping stats fix;
//         [16,31): psum 1875-row reduce to psum2 15 rows ----
__global__ void k_wl2(const float* __restrict__ x, const int* __restrict__ src1,
                      const int* __restrict__ dst1, const int* __restrict__ et1,
                      const float* __restrict__ W1, const int* __restrict__ cnt,
                      const int* __restrict__ list, const int* __restrict__ uc_slot,
                      float* __restrict__ hfix, float* __restrict__ statsfix,
                      const float* __restrict__ psum, float* __restrict__ psum2) {
    int b = blockIdx.x, tid = threadIdx.x;
    if (b >= 16) {
        int r = b - 16, base = r * 125;
        float S = 0.f;
        for (int i = 0; i < 125; i++) S += psum[(base + i) * 256 + tid];
        psum2[r * 256 + tid] = S;
        return;
    }
    int c = tid & 127, half = tid >> 7;
    int n = *cnt; if (n > WL_CAP) n = WL_CAP;
    for (int i = b * 2 + half; i < n; i += 32) {
        int e = list[i];
        int s = src1[e], d = dst1[e], t = et1[e];
        int slot = uc_slot[d];
        if (slot < 0 || slot >= UC_CAP) continue;
        float acc = 0.f;
        for (int k = 0; k < D; k++) acc += x[(size_t)s * D + k] * W1[(t * D + k) * D + c];
        float old = atomicAdd(&hfix[slot * D + c], acc);
        atomicAdd(&statsfix[c], acc);
        atomicAdd(&statsfix[128 + c], 2.f * old * acc + acc * acc);
    }
}

// ---- 4. block 0: CSR scan; block 1: BN params; [2,162): B-frag pack;
//         [162,170): uncached rows -> hb (pre-BN, f32-complete) ----
__global__ void k_mid(const int* __restrict__ ehist, int* __restrict__ rs,
                      int* __restrict__ rs2, const float* __restrict__ psum2,
                      const float* __restrict__ statsfix,
                      const float* __restrict__ gamma, const float* __restrict__ beta,
                      float* __restrict__ params,
                      const float* __restrict__ W2, const float* __restrict__ Wself2,
                      unsigned short* __restrict__ BF,
                      const int* __restrict__ nuc, const int* __restrict__ uc_node,
                      const float* __restrict__ hfix, unsigned short* __restrict__ hb) {
    int b = blockIdx.x, tid = threadIdx.x;
    if (b == 1) {
        if (tid < 128) {
            float S = statsfix[tid], SS = statsfix[128 + tid];
#pragma unroll
            for (int r = 0; r < 15; r++) {
                S += psum2[r * 256 + tid];
                SS += psum2[r * 256 + 128 + tid];
            }
            float mean = S / (float)N1;
            float var = SS / (float)N1 - mean * mean;
            float sc = gamma[tid] * rsqrtf(var + 1e-5f);
            params[tid] = sc;
            params[128 + tid] = beta[tid] - mean * sc;
        }
        return;
    }
    if (b >= 162) {
        int n = *nuc; if (n > UC_CAP) n = UC_CAP;
        int c = tid & 127, sub = tid >> 7;
        for (int slot = (b - 162) * 2 + sub; slot < n; slot += 16) {
            int node = uc_node[slot];
            hb[(size_t)node * D + c] = f2bf(hfix[slot * D + c]);
        }
        return;
    }
    if (b >= 2) {
        int idx = (b - 2) * 256 + tid;           // 5*16*64*8 = 40960 exactly
        int j = idx & 7, lane = (idx >> 3) & 63, sub = (idx >> 9) & 15, g = idx >> 13;
        int kt = sub >> 2, ct = sub & 3;
        int k = kt * 32 + (lane >> 4) * 8 + j;
        int col = ct * 16 + (lane & 15);
        float v = (g < 4) ? W2[(g * D + k) * DO + col] : Wself2[k * DO + col];
        BF[idx] = f2bf(v);
        return;
    }
    // b == 0: exclusive scan of ehist
    __shared__ int part[256];
    int lo = tid * 24, hi = lo + 24; if (hi > N2) hi = N2;
    int s = 0;
    for (int i = lo; i < hi; i++) s += ehist[i];
    part[tid] = s;
    __syncthreads();
    if (tid == 0) {
        int a = 0;
        for (int i = 0; i < 256; i++) { int v = part[i]; part[i] = a; a += v; }
        rs[N2] = a;
    }
    __syncthreads();
    int a = part[tid];
    for (int i = lo; i < hi; i++) { rs[i] = a; rs2[i] = a; a += ehist[i]; }
}

// ---- 5. CSR scatter of layer-2 edges ----
__global__ void k_escatter(const int* __restrict__ src2, const int* __restrict__ dst2,
                           const int* __restrict__ et2, int* __restrict__ rs2,
                           int* __restrict__ epay) {
    int e = blockIdx.x * blockDim.x + threadIdx.x;
    if (e >= E2) return;
    int d = dst2[e];
    int pos = atomicAdd(&rs2[d], 1);
    epay[pos] = src2[e] | (et2[e] << 16);
}

// ---- 6. aggregate: block-per-dst, 4 waves split the edge list, LDS reduce ----
#define AGG_ACC(P, V) { \
    int t_ = (P) >> 16; \
    float f0_ = fmaxf(bf2f((V) & 0xffff) * sc0 + sh0, 0.f); \
    float f1_ = fmaxf(bf2f((V) >> 16) * sc1 + sh1, 0.f); \
    acc[0][0] += (t_ == 0) ? f0_ : 0.f; acc[0][1] += (t_ == 0) ? f1_ : 0.f; \
    acc[1][0] += (t_ == 1) ? f0_ : 0.f; acc[1][1] += (t_ == 1) ? f1_ : 0.f; \
    acc[2][0] += (t_ == 2) ? f0_ : 0.f; acc[2][1] += (t_ == 2) ? f1_ : 0.f; \
    acc[3][0] += (t_ == 3) ? f0_ : 0.f; acc[3][1] += (t_ == 3) ? f1_ : 0.f; }

__global__ void __launch_bounds__(256) k_agg(const unsigned int* __restrict__ hbu,
                                             const int* __restrict__ rs,
                                             const int* __restrict__ epay,
                                             const float* __restrict__ params,
                                             unsigned int* __restrict__ aggbu) {
    __shared__ float red[4 * 4 * 128];          // [wave][rel][col] = 8 KB
    int d = blockIdx.x;
    int wave = threadIdx.x >> 6, lane = threadIdx.x & 63;
    float sc0 = params[2 * lane],       sh0 = params[128 + 2 * lane];
    float sc1 = params[2 * lane + 1],   sh1 = params[128 + 2 * lane + 1];
    float acc[4][2] = {};
    int j0 = rs[d], j1 = rs[d + 1];
    int j = j0 + wave;
    // 4 edges in flight per wave (stride 4 waves x 4 unroll = 16)
    for (; j + 12 < j1; j += 16) {
        int p0 = epay[j], p1 = epay[j + 4], p2 = epay[j + 8], p3 = epay[j + 12];
        unsigned int v0 = hbu[(size_t)(p0 & 0xffff) * 64 + lane];
        unsigned int v1 = hbu[(size_t)(p1 & 0xffff) * 64 + lane];
        unsigned int v2 = hbu[(size_t)(p2 & 0xffff) * 64 + lane];
        unsigned int v3 = hbu[(size_t)(p3 & 0xffff) * 64 + lane];
        AGG_ACC(p0, v0); AGG_ACC(p1, v1); AGG_ACC(p2, v2); AGG_ACC(p3, v3);
    }
    for (; j < j1; j += 4) {
        int p = epay[j];
        unsigned int v = hbu[(size_t)(p & 0xffff) * 64 + lane];
        AGG_ACC(p, v);
    }
#pragma unroll
    for (int t = 0; t < 4; t++) {
        red[(wave * 4 + t) * 128 + 2 * lane]     = acc[t][0];
        red[(wave * 4 + t) * 128 + 2 * lane + 1] = acc[t][1];
    }
    __syncthreads();
    // 256 threads: rel = tid>>6, col-pair = tid&63
    int t = threadIdx.x >> 6, l2 = threadIdx.x & 63;
    float s0 = 0.f, s1 = 0.f;
#pragma unroll
    for (int w = 0; w < 4; w++) {
        s0 += red[(w * 4 + t) * 128 + 2 * l2];
        s1 += red[(w * 4 + t) * 128 + 2 * l2 + 1];
    }
    unsigned int o = (unsigned int)f2bf(s0) | ((unsigned int)f2bf(s1) << 16);
    aggbu[((size_t)t * N2 + d) * 64 + l2] = o;
}

// ---- 7. out[d] = logsoftmax(b2 + relu(bn(hb[d]))@Wself2 + sum_t agg[t][d]@W2[t]) ----
__global__ void __launch_bounds__(256) k_gemm2(const unsigned short* __restrict__ aggb,
                                               const unsigned short* __restrict__ hb,
                                               const unsigned short* __restrict__ BF,
                                               const float* __restrict__ params,
                                               const float* __restrict__ b2,
                                               float* __restrict__ out) {
    int row0 = blockIdx.x * 64;
    int wave = threadIdx.x >> 6, lane = threadIdx.x & 63;
    int r = row0 + wave * 16 + (lane & 15);
    int rl = (r < N2) ? r : N2 - 1;
    int kb = (lane >> 4) * 8;
    f32x4 acc[4] = {};
#pragma unroll
    for (int kt = 0; kt < 4; kt++) {
#pragma unroll
        for (int g = 0; g < 5; g++) {
            bfrag8 a;
            if (g < 4) {
                a = *reinterpret_cast<const bfrag8*>(aggb + ((size_t)(g * N2 + rl) * D + kt * 32 + kb));
            } else {
                bfrag8 raw = *reinterpret_cast<const bfrag8*>(hb + ((size_t)rl * D + kt * 32 + kb));
#pragma unroll
                for (int j = 0; j < 8; j++) {
                    int c = kt * 32 + kb + j;
                    float f = bf2f((unsigned int)(unsigned short)raw[j]);
                    f = fmaxf(f * params[c] + params[128 + c], 0.f);
                    a[j] = (short)f2bf(f);
                }
            }
#pragma unroll
            for (int ct = 0; ct < 4; ct++) {
                bfrag8 bb = *reinterpret_cast<const bfrag8*>(BF + ((((g * 4 + kt) * 4 + ct) * 64 + lane) * 8));
                acc[ct] = __builtin_amdgcn_mfma_f32_16x16x32_bf16(a, bb, acc[ct], 0, 0, 0);
            }
        }
    }
    float bb4[4];
#pragma unroll
    for (int ct = 0; ct < 4; ct++) bb4[ct] = b2[ct * 16 + (lane & 15)];
    int srow = row0 + wave * 16 + (lane >> 4) * 4;
#pragma unroll
    for (int i = 0; i < 4; i++) {
        float v[4];
#pragma unroll
        for (int ct = 0; ct < 4; ct++) v[ct] = acc[ct][i] + bb4[ct];
        float m = fmaxf(fmaxf(v[0], v[1]), fmaxf(v[2], v[3]));
#pragma unroll
        for (int sh = 1; sh <= 8; sh <<= 1) m = fmaxf(m, __shfl_xor(m, sh, 64));
        float s = 0.f;
#pragma unroll
        for (int ct = 0; ct < 4; ct++) s += expf(v[ct] - m);
#pragma unroll
        for (int sh = 1; sh <= 8; sh <<= 1) s += __shfl_xor(s, sh, 64);
        float lg = m + logf(s);
        int rr = srow + i;
        if (rr < N2) {
#pragma unroll
            for (int ct = 0; ct < 4; ct++)
                out[(size_t)rr * DO + ct * 16 + (lane & 15)] = v[ct] - lg;
        }
    }
}

extern "C" void kernel_launch(void* const* d_in, const int* in_sizes, int n_in,
                              void* d_out, int out_size, void* d_ws, size_t ws_size,
                              hipStream_t stream) {
    const float* x      = (const float*)d_in[0];
    const int* src1     = (const int*)d_in[1];
    const int* dst1     = (const int*)d_in[2];
    const int* et1      = (const int*)d_in[3];
    const int* src2     = (const int*)d_in[4];
    const int* dst2     = (const int*)d_in[5];
    const int* et2      = (const int*)d_in[6];
    const int* hmap     = (const int*)d_in[7];
    const float* hist   = (const float*)d_in[8];
    const float* W1     = (const float*)d_in[9];
    const float* Wself1 = (const float*)d_in[10];
    const float* b1     = (const float*)d_in[11];
    const float* gamma  = (const float*)d_in[12];
    const float* beta   = (const float*)d_in[13];
    const float* W2     = (const float*)d_in[14];
    const float* Wself2 = (const float*)d_in[15];
    const float* b2     = (const float*)d_in[16];
    float* out = (float*)d_out;

    char* ws = (char*)d_ws;
    unsigned short* hb   = (unsigned short*)(ws);              // 15,360,000
    unsigned short* aggb = (unsigned short*)(ws + 15360000);   //  6,144,000
    unsigned short* BF   = (unsigned short*)(ws + 21504000);   //     81,920
    float* hfix          = (float*)(ws + 21585920);            //    131,072
    int* uc_node         = (int*)(ws + 21716992);              //      1,024
    int* uc_slot         = (int*)(ws + 21718016);              //    240,000
    int* epay            = (int*)(ws + 21958016);              //  1,200,000
    int* rs              = (int*)(ws + 23158016);              //     24,016
    int* rs2             = (int*)(ws + 23182032);              //     24,000
    float* psum          = (float*)(ws + 23206032);            //  1,920,000
    float* psum2         = (float*)(ws + 25126032);            //     15,360
    float* statsfix      = (float*)(ws + 25141392);            //      1,024
    int* cnt             = (int*)(ws + 25142416);              //          4
    int* nuc             = (int*)(ws + 25142420);              //          4
    int* ehist           = (int*)(ws + 25142424);              //     24,000
    int* list            = (int*)(ws + 25166424);              //    131,072
    float* params        = (float*)(ws + 25297496);            //      1,024

    k_zero<<<8, 256, 0, stream>>>(statsfix, cnt, nuc, ehist);
    k_phase1<<<INIT_BLOCKS + SCAN_BLOCKS, 256, 0, stream>>>(
        x, hmap, hist, Wself1, b1, hb, nuc, uc_slot, uc_node, hfix, psum,
        dst1, cnt, list, dst2, ehist);
    k_wl2<<<31, 256, 0, stream>>>(x, src1, dst1, et1, W1, cnt, list, uc_slot,
                                  hfix, statsfix, psum, psum2);
    k_mid<<<170, 256, 0, stream>>>(ehist, rs, rs2, psum2, statsfix, gamma, beta,
                                   params, W2, Wself2, BF, nuc, uc_node, hfix, hb);
    k_escatter<<<(E2 + 255) / 256, 256, 0, stream>>>(src2, dst2, et2, rs2, epay);
    k_agg<<<N2, 256, 0, stream>>>((const unsigned int*)hb, rs, epay, params,
                                  (unsigned int*)aggb);
    k_gemm2<<<94, 256, 0, stream>>>(aggb, hb, BF, params, b2, out);
}